// Round 3
// baseline (62.304 us; speedup 1.0000x reference)
//
#include <hip/hip_runtime.h>

typedef __attribute__((ext_vector_type(8))) short bf16x8;
typedef __attribute__((ext_vector_type(4))) float f32x4;

#define GAMMA_ 0.5f
#define LOG2E_ 1.4426950408889634f

constexpr int D      = 256;   // feature dim
constexpr int BM     = 128;   // rows of X per block (A panel, full-K resident)
constexpr int BN     = 64;    // X_train rows per B stage tile
constexpr int BK     = 64;    // K-chunk per B stage
constexpr int JSPLIT = 8;     // split of M across blockIdx.y

// ---------- helpers ----------
__device__ __forceinline__ unsigned short f2bf(float f) {
    unsigned int x = __float_as_uint(f);
    x += 0x7FFFu + ((x >> 16) & 1u);          // RNE
    return (unsigned short)(x >> 16);
}

__device__ __forceinline__ void gload16(void* lds, const void* g) {
    __builtin_amdgcn_global_load_lds(
        (const __attribute__((address_space(1))) void*)g,
        (__attribute__((address_space(3))) void*)lds, 16, 0, 0);
}

// ---------- prep: cast to bf16, row |x|^2, coefs, out-init ----------
__global__ void prep_all_kernel(const float* __restrict__ X,
                                const float* __restrict__ Xt,
                                const float* __restrict__ alphas,
                                const float* __restrict__ y,
                                const float* __restrict__ b,
                                unsigned short* __restrict__ Abf,
                                unsigned short* __restrict__ Bbf,
                                float* __restrict__ srow,
                                float* __restrict__ tcol,
                                float* __restrict__ coef,
                                float* __restrict__ out,
                                int N, int M) {
    int w = threadIdx.x >> 6;         // one wave per row
    int l = threadIdx.x & 63;
    int row = blockIdx.x * 4 + w;
    if (row >= N + M) return;
    const float* src;
    unsigned short* dst;
    if (row < N) { src = X  + (size_t)row * D;       dst = Abf + (size_t)row * D; }
    else         { src = Xt + (size_t)(row - N) * D; dst = Bbf + (size_t)(row - N) * D; }
    const float4 v = reinterpret_cast<const float4*>(src)[l];
    ushort4 u;
    u.x = f2bf(v.x); u.y = f2bf(v.y); u.z = f2bf(v.z); u.w = f2bf(v.w);
    reinterpret_cast<ushort4*>(dst)[l] = u;
    float ss = v.x * v.x + v.y * v.y + v.z * v.z + v.w * v.w;
    #pragma unroll
    for (int off = 32; off >= 1; off >>= 1) ss += __shfl_xor(ss, off);
    if (l == 0) {
        float folded = -GAMMA_ * LOG2E_ * ss;
        if (row < N) { srow[row] = folded; out[row] = b[0]; }
        else {
            int r2 = row - N;
            tcol[r2] = folded;
            coef[r2] = alphas[r2] * y[r2];
        }
    }
}

// ---------- fused RBF-SVM predict ----------
// pred_i = sum_j exp2( s_i + t_j + (2*g*log2e) * <x_i, xt_j> ) * coef_j + b
__launch_bounds__(256, 2)
__global__ void svm_main_kernel(const unsigned short* __restrict__ Abf,
                                const unsigned short* __restrict__ Bbf,
                                const float* __restrict__ srow,
                                const float* __restrict__ tcol,
                                const float* __restrict__ coef,
                                float* __restrict__ out,
                                int M) {
    __shared__ char As[BM * 512];       // 64 KiB: full-K A panel (swizzled image)
    __shared__ char Bs[2 * BN * 128];   // 16 KiB: double-buffered B k-tiles

    const int tid = threadIdx.x;
    const int w   = tid >> 6;          // wave 0..3
    const int l   = tid & 63;
    const int wr  = w >> 1;            // 2x2 wave grid, wave tile 64x32
    const int wc  = w & 1;
    const int hi  = l >> 4;            // 0..3
    const int lo  = l & 15;
    const int row0  = blockIdx.x * BM;
    const int jspan = M / JSPLIT;      // 1024
    const int jbase = blockIdx.y * jspan;
    const int JT    = jspan / BN;      // 16 B j-tiles per block

    // ---- stage A panel once: linear LDS dest, inverse-swizzled global src ----
    {
        const char* Ab = (const char*)Abf + (size_t)row0 * 512;
        #pragma unroll
        for (int c = 0; c < 16; ++c) {
            int x   = c * 4096 + tid * 16;           // linear LDS byte offset
            int row = x >> 9;                        // 512 B per row
            int src = row * 512 + ((x & 511) ^ ((row & 7) << 4));
            gload16(As + c * 4096 + w * 1024, Ab + src);
        }
    }

    const char* Bb = (const char*)Bbf + (size_t)jbase * 512;
    // issue one B stage (8 KB): 2 gload16 per thread, linear dest + pre-swizzled src
    auto issueB = [&](int jt2, int kt2, int buf) {
        #pragma unroll
        for (int c = 0; c < 2; ++c) {
            int x   = c * 4096 + tid * 16;
            int col = x >> 7;                        // 128 B per col-row
            int src = (jt2 * BN + col) * 512 + kt2 * 128
                    + ((x & 127) ^ ((col & 7) << 4));
            gload16(Bs + buf * 8192 + c * 4096 + w * 1024, Bb + src);
        }
    };
    issueB(0, 0, 0);   // prologue: stage 0 in flight

    // per-lane row constants (row = row0 + wr*64 + mi*16 + hi*4 + r)
    float sreg[4][4];
    #pragma unroll
    for (int mi = 0; mi < 4; ++mi)
        #pragma unroll
        for (int r = 0; r < 4; ++r)
            sreg[mi][r] = srow[row0 + wr * 64 + mi * 16 + hi * 4 + r];

    float partial[4][4];
    #pragma unroll
    for (int mi = 0; mi < 4; ++mi)
        #pragma unroll
        for (int r = 0; r < 4; ++r) partial[mi][r] = 0.0f;

    const float K2G = 2.0f * GAMMA_ * LOG2E_;

    for (int jt = 0; jt < JT; ++jt) {
        f32x4 acc[4][2];
        #pragma unroll
        for (int mi = 0; mi < 4; ++mi)
            #pragma unroll
            for (int ni = 0; ni < 2; ++ni) {
                f32x4 z = {0.f, 0.f, 0.f, 0.f};
                acc[mi][ni] = z;
            }
        float treg[2], creg[2];

        #pragma unroll
        for (int kt = 0; kt < 4; ++kt) {
            const int buf = kt & 1;                  // s = jt*4+kt, jt*4 even
            // ---- prefetch next stage, counted vmcnt (never 0 mid-loop) ----
            if (kt < 3) {
                issueB(jt, kt + 1, buf ^ 1);
                asm volatile("s_waitcnt vmcnt(2)" ::: "memory");
            } else if (jt + 1 < JT) {
                issueB(jt + 1, 0, buf ^ 1);
                asm volatile("s_waitcnt vmcnt(2)" ::: "memory");
            } else {
                asm volatile("s_waitcnt vmcnt(0)" ::: "memory");
            }
            __builtin_amdgcn_s_barrier();            // stage-kt data visible to all

            if (kt == 0) {   // per-jt column constants (drained by later waits)
                #pragma unroll
                for (int ni = 0; ni < 2; ++ni) {
                    int colg = jbase + jt * BN + wc * 32 + ni * 16 + lo;
                    treg[ni] = tcol[colg];
                    creg[ni] = coef[colg];
                }
            }

            #pragma unroll
            for (int ks = 0; ks < 2; ++ks) {
                const int kg = kt * 2 + ks;          // global 32-elem K chunk
                bf16x8 a[4], bb[2];
                #pragma unroll
                for (int mi = 0; mi < 4; ++mi) {
                    int row = wr * 64 + mi * 16 + lo;
                    int off = row * 512 + kg * 64 + hi * 16;
                    off ^= (row & 7) << 4;
                    a[mi] = *(const bf16x8*)(As + off);
                }
                #pragma unroll
                for (int ni = 0; ni < 2; ++ni) {
                    int col = wc * 32 + ni * 16 + lo;
                    int off = buf * 8192 + col * 128
                            + ((ks * 64 + hi * 16) ^ ((col & 7) << 4));
                    bb[ni] = *(const bf16x8*)(Bs + off);
                }
                __builtin_amdgcn_s_setprio(1);
                #pragma unroll
                for (int mi = 0; mi < 4; ++mi)
                    #pragma unroll
                    for (int ni = 0; ni < 2; ++ni)
                        acc[mi][ni] = __builtin_amdgcn_mfma_f32_16x16x32_bf16(
                            a[mi], bb[ni], acc[mi][ni], 0, 0, 0);
                __builtin_amdgcn_s_setprio(0);
            }
            __builtin_amdgcn_s_barrier();            // all reads of buf done
        }

        // ---- fused epilogue (registers only): exp + weighted row-accumulate ----
        #pragma unroll
        for (int ni = 0; ni < 2; ++ni) {
            #pragma unroll
            for (int mi = 0; mi < 4; ++mi) {
                #pragma unroll
                for (int r = 0; r < 4; ++r) {
                    float arg = fmaf(acc[mi][ni][r], K2G, sreg[mi][r] + treg[ni]);
                    float p = __builtin_amdgcn_exp2f(arg);
                    partial[mi][r] = fmaf(p, creg[ni], partial[mi][r]);
                }
            }
        }
    }

    // ---- reduce across 16 lanes per row, then one atomicAdd per row ----
    #pragma unroll
    for (int mi = 0; mi < 4; ++mi) {
        #pragma unroll
        for (int r = 0; r < 4; ++r) {
            float v = partial[mi][r];
            v += __shfl_xor(v, 1);
            v += __shfl_xor(v, 2);
            v += __shfl_xor(v, 4);
            v += __shfl_xor(v, 8);
            if (lo == 0) {
                int rowg = row0 + wr * 64 + mi * 16 + hi * 4 + r;
                atomicAdd(&out[rowg], v);
            }
        }
    }
}

// ---------- launcher ----------
extern "C" void kernel_launch(void* const* d_in, const int* in_sizes, int n_in,
                              void* d_out, int out_size, void* d_ws, size_t ws_size,
                              hipStream_t stream) {
    const float* X      = (const float*)d_in[0];
    const float* Xt     = (const float*)d_in[1];
    const float* alphas = (const float*)d_in[2];
    const float* y      = (const float*)d_in[3];
    const float* b      = (const float*)d_in[4];
    float* out = (float*)d_out;

    const int N = in_sizes[0] / D;   // 8192
    const int M = in_sizes[1] / D;   // 8192

    // workspace: bf16 X | bf16 Xt | srow[N] | tcol[M] | coef[M]
    char* ws = (char*)d_ws;
    unsigned short* Abf = (unsigned short*)ws;
    unsigned short* Bbf = Abf + (size_t)N * D;
    float* srow = (float*)(Bbf + (size_t)M * D);
    float* tcol = srow + N;
    float* coef = tcol + M;

    prep_all_kernel<<<(N + M) / 4, 256, 0, stream>>>(X, Xt, alphas, y, b,
                                                     Abf, Bbf, srow, tcol, coef,
                                                     out, N, M);

    dim3 grid(N / BM, JSPLIT);
    svm_main_kernel<<<grid, 256, 0, stream>>>(Abf, Bbf, srow, tcol, coef, out, M);
}

// Round 4
// 53.476 us; speedup vs baseline: 1.1651x; 1.1651x over previous
//
#include <hip/hip_runtime.h>

typedef __attribute__((ext_vector_type(8))) short bf16x8;
typedef __attribute__((ext_vector_type(4))) float f32x4;

#define GAMMA_ 0.5f
#define LOG2E_ 1.4426950408889634f

constexpr int D      = 256;   // feature dim (K)
constexpr int BM     = 128;   // rows of X per block
constexpr int BN     = 128;   // X_train rows per j-tile
constexpr int JSPLIT = 8;     // split of M across blockIdx.y

// LDS layout (bytes):
//   [0, 65536)      : 4-slot B ring (4 x 16 KiB); also used once as A panel
//   [65536, 66048)  : srow panel  (128 x f32)
//   [66048, 70144)  : tcol panel  (1024 x f32)
//   [70144, 74240)  : coef panel  (1024 x f32)
constexpr int AUX_SROW  = 65536;
constexpr int AUX_TCOL  = 66048;
constexpr int AUX_COEF  = 70144;
constexpr int LDS_BYTES = 74240;

// ---------- helpers ----------
__device__ __forceinline__ unsigned short f2bf(float f) {
    unsigned int x = __float_as_uint(f);
    x += 0x7FFFu + ((x >> 16) & 1u);          // RNE
    return (unsigned short)(x >> 16);
}

__device__ __forceinline__ void gload16(void* lds, const void* g) {
    __builtin_amdgcn_global_load_lds(
        (const __attribute__((address_space(1))) void*)g,
        (__attribute__((address_space(3))) void*)lds, 16, 0, 0);
}

// ---------- prep: cast to bf16, row |x|^2, coefs, out-init ----------
__global__ void prep_all_kernel(const float* __restrict__ X,
                                const float* __restrict__ Xt,
                                const float* __restrict__ alphas,
                                const float* __restrict__ y,
                                const float* __restrict__ b,
                                unsigned short* __restrict__ Abf,
                                unsigned short* __restrict__ Bbf,
                                float* __restrict__ srow,
                                float* __restrict__ tcol,
                                float* __restrict__ coef,
                                float* __restrict__ out,
                                int N, int M) {
    int w = threadIdx.x >> 6;         // one wave per row
    int l = threadIdx.x & 63;
    int row = blockIdx.x * 4 + w;
    if (row >= N + M) return;
    const float* src;
    unsigned short* dst;
    if (row < N) { src = X  + (size_t)row * D;       dst = Abf + (size_t)row * D; }
    else         { src = Xt + (size_t)(row - N) * D; dst = Bbf + (size_t)(row - N) * D; }
    const float4 v = reinterpret_cast<const float4*>(src)[l];
    ushort4 u;
    u.x = f2bf(v.x); u.y = f2bf(v.y); u.z = f2bf(v.z); u.w = f2bf(v.w);
    reinterpret_cast<ushort4*>(dst)[l] = u;
    float ss = v.x * v.x + v.y * v.y + v.z * v.z + v.w * v.w;
    #pragma unroll
    for (int off = 32; off >= 1; off >>= 1) ss += __shfl_xor(ss, off);
    if (l == 0) {
        float folded = -GAMMA_ * LOG2E_ * ss;
        if (row < N) { srow[row] = folded; out[row] = b[0]; }
        else {
            int r2 = row - N;
            tcol[r2] = folded;
            coef[r2] = alphas[r2] * y[r2];
        }
    }
}

// ---------- fused RBF-SVM predict ----------
// pred_i = sum_j exp2( s_i + t_j + (2*g*log2e) * <x_i, xt_j> ) * coef_j + b
__launch_bounds__(256, 2)
__global__ void svm_main_kernel(const unsigned short* __restrict__ Abf,
                                const unsigned short* __restrict__ Bbf,
                                const float* __restrict__ srow,
                                const float* __restrict__ tcol,
                                const float* __restrict__ coef,
                                float* __restrict__ out,
                                int M) {
    __shared__ char L[LDS_BYTES];

    const int tid = threadIdx.x;
    const int w   = tid >> 6;          // wave 0..3
    const int l   = tid & 63;
    const int wr  = w >> 1;            // 2x2 wave grid, wave tile 64x64
    const int wc  = w & 1;
    const int hi  = l >> 4;            // 0..3
    const int lo  = l & 15;
    const int row0  = blockIdx.x * BM;
    const int jspan = M / JSPLIT;      // 1024
    const int jbase = blockIdx.y * jspan;
    const int JT    = jspan / BN;      // 8 j-tiles per block

    // ---- prologue: stage A panel (64 KiB) into ring region, swizzled image ----
    {
        const char* Ab = (const char*)Abf + (size_t)row0 * 512;
        #pragma unroll
        for (int c = 0; c < 16; ++c) {
            int x   = c * 4096 + tid * 16;           // linear LDS byte offset
            int row = x >> 9;                        // 512 B per row
            int src = row * 512 + ((x & 511) ^ ((row & 7) << 4));
            gload16(L + c * 4096 + w * 1024, Ab + src);
        }
    }
    // ---- stage srow/tcol/coef aux panels ----
    if (w == 0 && l < 32)
        gload16(L + AUX_SROW, (const char*)(srow + row0) + l * 16);
    gload16(L + AUX_TCOL + w * 1024, (const char*)(tcol + jbase) + tid * 16);
    gload16(L + AUX_COEF + w * 1024, (const char*)(coef + jbase) + tid * 16);
    __syncthreads();   // full drain: A + aux panels visible

    // ---- load this wave's A fragments into registers (held whole kernel) ----
    bf16x8 areg[4][8];
    #pragma unroll
    for (int mi = 0; mi < 4; ++mi) {
        int row = wr * 64 + mi * 16 + lo;
        #pragma unroll
        for (int kg = 0; kg < 8; ++kg) {
            int off = (row * 512 + kg * 64 + hi * 16) ^ ((row & 7) << 4);
            areg[mi][kg] = *(const bf16x8*)(L + off);
        }
    }
    __syncthreads();   // all waves done reading A before ring overwrites it

    // ---- B ring staging: 16 KiB/stage, 4 gload16/thread ----
    const char* Bb = (const char*)Bbf + (size_t)jbase * 512;
    auto issueB = [&](int jt2, int kt2, int slot) {
        #pragma unroll
        for (int c = 0; c < 4; ++c) {
            int x   = c * 4096 + tid * 16;
            int col = x >> 7;                        // 128 B per (col, kt) row
            int src = (jt2 * BN + col) * 512 + kt2 * 128
                    + ((x & 127) ^ ((col & 7) << 4));
            gload16(L + slot * 16384 + c * 4096 + w * 1024, Bb + src);
        }
    };
    issueB(0, 0, 0);
    issueB(0, 1, 1);
    issueB(0, 2, 2);   // 12 loads outstanding (3 stages deep)

    float partial[4][4];
    #pragma unroll
    for (int mi = 0; mi < 4; ++mi)
        #pragma unroll
        for (int r = 0; r < 4; ++r) partial[mi][r] = 0.0f;

    const float K2G = 2.0f * GAMMA_ * LOG2E_;

    for (int jt = 0; jt < JT; ++jt) {
        f32x4 acc[4][4];
        #pragma unroll
        for (int mi = 0; mi < 4; ++mi)
            #pragma unroll
            for (int ni = 0; ni < 4; ++ni) {
                f32x4 z = {0.f, 0.f, 0.f, 0.f};
                acc[mi][ni] = z;
            }

        #pragma unroll
        for (int kt = 0; kt < 4; ++kt) {             // stage s = jt*4 + kt
            const int slot = kt;                     // s & 3 == kt
            // issue stage s+3 (slot (kt+3)&3 = previous stage's slot, safe)
            const int jt2 = jt + ((kt + 3) >> 2);
            const int kt2 = (kt + 3) & 3;
            if (jt2 < JT) {
                issueB(jt2, kt2, (kt + 3) & 3);
                asm volatile("s_waitcnt vmcnt(12)" ::: "memory");  // stage s done
            } else if (kt == 1) {
                asm volatile("s_waitcnt vmcnt(8)" ::: "memory");
            } else if (kt == 2) {
                asm volatile("s_waitcnt vmcnt(4)" ::: "memory");
            } else {
                asm volatile("s_waitcnt vmcnt(0)" ::: "memory");
            }
            __builtin_amdgcn_s_barrier();            // stage-s B visible to all

            #pragma unroll
            for (int ks = 0; ks < 2; ++ks) {
                bf16x8 bb[4];
                #pragma unroll
                for (int ni = 0; ni < 4; ++ni) {
                    int col = wc * 64 + ni * 16 + lo;
                    int off = slot * 16384 + col * 128
                            + ((ks * 64 + hi * 16) ^ ((col & 7) << 4));
                    bb[ni] = *(const bf16x8*)(L + off);
                }
                __builtin_amdgcn_s_setprio(1);
                #pragma unroll
                for (int mi = 0; mi < 4; ++mi)
                    #pragma unroll
                    for (int ni = 0; ni < 4; ++ni)
                        acc[mi][ni] = __builtin_amdgcn_mfma_f32_16x16x32_bf16(
                            areg[mi][kt * 2 + ks], bb[ni], acc[mi][ni], 0, 0, 0);
                __builtin_amdgcn_s_setprio(0);
            }
            __builtin_amdgcn_s_barrier();            // all reads of slot done
        }

        // ---- fused epilogue (regs + LDS aux): exp + weighted row-accumulate ----
        float sv[4][4];
        #pragma unroll
        for (int mi = 0; mi < 4; ++mi)
            #pragma unroll
            for (int r = 0; r < 4; ++r)
                sv[mi][r] = *(const float*)(L + AUX_SROW
                               + (wr * 64 + mi * 16 + hi * 4 + r) * 4);
        #pragma unroll
        for (int ni = 0; ni < 4; ++ni) {
            int cl = jt * BN + wc * 64 + ni * 16 + lo;
            float t  = *(const float*)(L + AUX_TCOL + cl * 4);
            float cf = *(const float*)(L + AUX_COEF + cl * 4);
            #pragma unroll
            for (int mi = 0; mi < 4; ++mi) {
                #pragma unroll
                for (int r = 0; r < 4; ++r) {
                    float arg = fmaf(acc[mi][ni][r], K2G, sv[mi][r] + t);
                    float p = __builtin_amdgcn_exp2f(arg);
                    partial[mi][r] = fmaf(p, cf, partial[mi][r]);
                }
            }
        }
    }

    // ---- reduce across 16 lanes per row, then one atomicAdd per row ----
    #pragma unroll
    for (int mi = 0; mi < 4; ++mi) {
        #pragma unroll
        for (int r = 0; r < 4; ++r) {
            float v = partial[mi][r];
            v += __shfl_xor(v, 1);
            v += __shfl_xor(v, 2);
            v += __shfl_xor(v, 4);
            v += __shfl_xor(v, 8);
            if (lo == 0) {
                int rowg = row0 + wr * 64 + mi * 16 + hi * 4 + r;
                atomicAdd(&out[rowg], v);
            }
        }
    }
}

// ---------- launcher ----------
extern "C" void kernel_launch(void* const* d_in, const int* in_sizes, int n_in,
                              void* d_out, int out_size, void* d_ws, size_t ws_size,
                              hipStream_t stream) {
    const float* X      = (const float*)d_in[0];
    const float* Xt     = (const float*)d_in[1];
    const float* alphas = (const float*)d_in[2];
    const float* y      = (const float*)d_in[3];
    const float* b      = (const float*)d_in[4];
    float* out = (float*)d_out;

    const int N = in_sizes[0] / D;   // 8192
    const int M = in_sizes[1] / D;   // 8192

    // workspace: bf16 X | bf16 Xt | srow[N] | tcol[M] | coef[M]
    char* ws = (char*)d_ws;
    unsigned short* Abf = (unsigned short*)ws;
    unsigned short* Bbf = Abf + (size_t)N * D;
    float* srow = (float*)(Bbf + (size_t)M * D);
    float* tcol = srow + N;
    float* coef = tcol + M;

    prep_all_kernel<<<(N + M) / 4, 256, 0, stream>>>(X, Xt, alphas, y, b,
                                                     Abf, Bbf, srow, tcol, coef,
                                                     out, N, M);

    dim3 grid(N / BM, JSPLIT);
    svm_main_kernel<<<grid, 256, 0, stream>>>(Abf, Bbf, srow, tcol, coef, out, M);
}